// Round 2
// 740.000 us; speedup vs baseline: 1.0607x; 1.0607x over previous
//
#include <hip/hip_runtime.h>
#include <hip/hip_bf16.h>

#define B_  4
#define T_  256
#define U_  64
#define D_  512
#define INNER_ 512
#define VOCAB_ 2048

// ---------------- types ----------------
typedef __attribute__((ext_vector_type(8))) short short8;   // 8 bf16 (4 VGPRs)
typedef __attribute__((ext_vector_type(4))) float f32x4;

// ---------------- pass 1: projections (fp32) ----------------
__global__ __launch_bounds__(256) void proj_kernel(
    const float* __restrict__ enc, const float* __restrict__ dec,
    const float* __restrict__ W1, const float* __restrict__ b1,
    float* __restrict__ encP, float* __restrict__ decPb) {
  int ct = blockIdx.x;   // 0..3 col tiles of 128
  int rt = blockIdx.y;   // 0..79 row tiles of 16 (64 enc + 16 dec)
  const float* src; float* dst; int kOff; int addB1; int rowBase;
  if (rt < 64) { src = enc; dst = encP; kOff = 0; addB1 = 0; rowBase = rt * 16; }
  else { src = dec; dst = decPb; kOff = D_; addB1 = 1; rowBase = (rt - 64) * 16; }

  __shared__ float As[16][D_];  // 32 KiB
  int tid = threadIdx.x;
  const float4* s4 = (const float4*)(src + (size_t)rowBase * D_);
  float4* a4 = (float4*)(&As[0][0]);
#pragma unroll
  for (int i = 0; i < 8; i++) a4[tid + 256 * i] = s4[tid + 256 * i];
  __syncthreads();

  int colQ = (tid & 31) * 4;        // 4 consecutive cols within 128-tile
  int col = ct * 128 + colQ;
  int r0 = (tid >> 5) * 2;          // 2 rows
  float a00=0,a01=0,a02=0,a03=0, a10=0,a11=0,a12=0,a13=0;
  const float* Wp = W1 + (size_t)kOff * INNER_ + col;
#pragma unroll 4
  for (int k = 0; k < D_; k++) {
    float4 w = *(const float4*)(Wp + (size_t)k * INNER_);
    float e0 = As[r0][k], e1 = As[r0 + 1][k];
    a00 += e0 * w.x; a01 += e0 * w.y; a02 += e0 * w.z; a03 += e0 * w.w;
    a10 += e1 * w.x; a11 += e1 * w.y; a12 += e1 * w.z; a13 += e1 * w.w;
  }
  float4 bb = {0,0,0,0};
  if (addB1) bb = *(const float4*)(b1 + col);
  float4 o0 = {a00 + bb.x, a01 + bb.y, a02 + bb.z, a03 + bb.w};
  float4 o1 = {a10 + bb.x, a11 + bb.y, a12 + bb.z, a13 + bb.w};
  *(float4*)(dst + (size_t)(rowBase + r0) * INNER_ + col) = o0;
  *(float4*)(dst + (size_t)(rowBase + r0 + 1) * INNER_ + col) = o1;
}

// ---------------- pass 1b: W2 (512x2048 f32) -> W2T (2048x512 bf16) ----------------
__global__ __launch_bounds__(256) void w2t_kernel(
    const float* __restrict__ W2, __hip_bfloat16* __restrict__ W2T) {
  __shared__ float tile[32][33];
  int vBase = blockIdx.x * 32;  // 64
  int kBase = blockIdx.y * 32;  // 16
  int tx = threadIdx.x & 31, ty = threadIdx.x >> 5;  // 32 x 8
#pragma unroll
  for (int i = 0; i < 32; i += 8)
    tile[ty + i][tx] = W2[(size_t)(kBase + ty + i) * VOCAB_ + vBase + tx];
  __syncthreads();
#pragma unroll
  for (int i = 0; i < 32; i += 8)
    W2T[(size_t)(vBase + ty + i) * INNER_ + kBase + tx] = __float2bfloat16(tile[tx][ty + i]);
}

// ---------------- pass 2: hidden H[r][k] = tanh(encP[bt][k] + decPb[b*64+u][k]) ----------------
__global__ __launch_bounds__(256) void hidden_kernel(
    const float* __restrict__ encP, const float* __restrict__ decPb,
    __hip_bfloat16* __restrict__ H) {
  int gid = blockIdx.x * 256 + threadIdx.x;  // 4,194,304 total
  int k0 = (gid & 63) * 8;
  int r = gid >> 6;            // row in [0, 65536)
  int u = r & 63;
  int bt = r >> 6;             // b*T + t
  int b = bt >> 8;             // T = 256
  const float4* e = (const float4*)(encP + (size_t)bt * 512 + k0);
  const float4* dv = (const float4*)(decPb + (size_t)(b * 64 + u) * 512 + k0);
  float4 e0 = e[0], e1 = e[1];
  float4 d0 = dv[0], d1 = dv[1];
  union { __hip_bfloat16 h[8]; uint4 v; } p;
  p.h[0] = __float2bfloat16(tanhf(e0.x + d0.x));
  p.h[1] = __float2bfloat16(tanhf(e0.y + d0.y));
  p.h[2] = __float2bfloat16(tanhf(e0.z + d0.z));
  p.h[3] = __float2bfloat16(tanhf(e0.w + d0.w));
  p.h[4] = __float2bfloat16(tanhf(e1.x + d1.x));
  p.h[5] = __float2bfloat16(tanhf(e1.y + d1.y));
  p.h[6] = __float2bfloat16(tanhf(e1.z + d1.z));
  p.h[7] = __float2bfloat16(tanhf(e1.w + d1.w));
  *(uint4*)((__hip_bfloat16*)H + (size_t)r * 512 + k0) = p.v;
}

// ---------------- pass 3: main GEMM: out = H(65536x512) * W2T^T + b2 ----------------
// 256x256 tile, 8 waves (2x4), BK=64, double-buffered LDS (128 KiB),
// counted vmcnt (T4), XOR-swizzled LDS via pre-swizzled global source (T2),
// setprio around MFMA clusters (T5), bijective XCD swizzle (T1).
__device__ inline void gload_lds16(const void* g, void* l) {
  __builtin_amdgcn_global_load_lds(
      (const __attribute__((address_space(1))) unsigned int*)g,
      (__attribute__((address_space(3))) unsigned int*)l, 16, 0, 0);
}

__global__ __launch_bounds__(512, 2) void joint_gemm(
    const __hip_bfloat16* __restrict__ H, const __hip_bfloat16* __restrict__ W2T,
    const float* __restrict__ b2, float* __restrict__ out) {
  extern __shared__ char smem[];  // 128 KiB: A[2][256][64] bf16, B[2][256][64] bf16
  int tid = threadIdx.x;
  int lane = tid & 63, wave = tid >> 6;     // 8 waves
  int wm = wave >> 2, wn = wave & 3;        // 2 x 4 wave grid; per-wave 128x64 output

  // T1: XCD-aware bijective swizzle, nwg = 2048 (divisible by 8)
  int bid = blockIdx.x;
  int wg = (bid & 7) * 256 + (bid >> 3);
  int rt = wg >> 3;          // 0..255 (M tiles)
  int ct = wg & 7;           // 0..7   (N tiles)
  size_t rowBase = (size_t)rt * 256;
  int colBase = ct * 256;

  // ---- staging setup (per-thread) ----
  // Thread stages rows j*64 + (tid>>3), swizzled k-slot (tid&7)^(row&7).
  // LDS dest stays linear (global_load_lds requirement); source is pre-swizzled.
  int srow = tid >> 3;                          // 0..63
  int kswz = ((tid & 7) ^ (srow & 7)) * 8;      // bf16 element offset within 64-wide k
  const __hip_bfloat16* pA = H   + (rowBase + srow) * 512 + kswz;
  const __hip_bfloat16* pB = W2T + (size_t)(colBase + srow) * 512 + kswz;
  __hip_bfloat16* ldsA = (__hip_bfloat16*)smem;
  __hip_bfloat16* ldsB = (__hip_bfloat16*)(smem + 65536);
  int stageRow = wave * 8;  // wave-uniform LDS base row within each 64-row unit

#define STAGE(t, buf) do {                                                    \
    const __hip_bfloat16* ga = pA + (size_t)(t) * 64;                         \
    const __hip_bfloat16* gb = pB + (size_t)(t) * 64;                         \
    __hip_bfloat16* la = ldsA + (buf) * 16384 + stageRow * 64;                \
    __hip_bfloat16* lb = ldsB + (buf) * 16384 + stageRow * 64;                \
    _Pragma("unroll")                                                         \
    for (int j = 0; j < 4; j++) {                                             \
      gload_lds16(ga + (size_t)j * 64 * 512, la + j * 64 * 64);               \
      gload_lds16(gb + (size_t)j * 64 * 512, lb + j * 64 * 64);               \
    } } while (0)

  // ---- fragment ds_read byte offsets (swizzle-matched) ----
  // frag row r, k-slot gs = ks*4 + (lane>>4): byte = r*128 + ((gs*16) ^ ((r&7)*16))
  int lrA = wm * 128 + (lane & 15);
  int lrB = wn * 64 + (lane & 15);
  int sx = (lane & 7) * 16;                 // (r&7)*16 — same for all mi/ni (steps of 16 rows)
  int q16 = (lane >> 4) * 16;
  int offA0 = lrA * 128 + (q16 ^ sx);
  int offA1 = lrA * 128 + ((64 + q16) ^ sx);
  int offB0 = lrB * 128 + (q16 ^ sx);
  int offB1 = lrB * 128 + ((64 + q16) ^ sx);

  // ---- acc init with bias ----
  float bv[4];
#pragma unroll
  for (int ni = 0; ni < 4; ni++) bv[ni] = b2[colBase + wn * 64 + ni * 16 + (lane & 15)];
  f32x4 acc[8][4];
#pragma unroll
  for (int mi = 0; mi < 8; mi++)
#pragma unroll
    for (int ni = 0; ni < 4; ni++)
      acc[mi][ni] = (f32x4){bv[ni], bv[ni], bv[ni], bv[ni]};

  // drain bias loads so the vmcnt bookkeeping below is exact
  asm volatile("s_waitcnt vmcnt(0)" ::: "memory");
  __builtin_amdgcn_sched_barrier(0);

  // prologue: tiles 0 and 1 in flight (8 loads/wave each)
  STAGE(0, 0);
  STAGE(1, 1);

  // Per K-tile: vmcnt(8)+barrier (tile landed) -> ds_read frags -> MFMA lo ->
  // ds_read hi -> lgkmcnt(0)+barrier (all reads done) -> restage t+2 into this
  // buffer -> MFMA hi. Loads for t+1 stay in flight across everything (T4).
#define KITER(t, buf, VMC, DOSTAGE) do {                                      \
    asm volatile("s_waitcnt vmcnt(" #VMC ")" ::: "memory");                   \
    __builtin_amdgcn_sched_barrier(0);                                        \
    __builtin_amdgcn_s_barrier();                                             \
    __builtin_amdgcn_sched_barrier(0);                                        \
    const char* baA = (const char*)ldsA + (buf) * 32768;                      \
    const char* baB = (const char*)ldsB + (buf) * 32768;                      \
    short8 bfr[4][2], afr[4][2];                                              \
    _Pragma("unroll") for (int ni = 0; ni < 4; ni++) {                        \
      bfr[ni][0] = *(const short8*)(baB + offB0 + ni * 2048);                 \
      bfr[ni][1] = *(const short8*)(baB + offB1 + ni * 2048); }               \
    _Pragma("unroll") for (int mi = 0; mi < 4; mi++) {                        \
      afr[mi][0] = *(const short8*)(baA + offA0 + mi * 2048);                 \
      afr[mi][1] = *(const short8*)(baA + offA1 + mi * 2048); }               \
    __builtin_amdgcn_s_setprio(1);                                            \
    _Pragma("unroll") for (int mi = 0; mi < 4; mi++)                          \
      _Pragma("unroll") for (int ni = 0; ni < 4; ni++) {                      \
        acc[mi][ni] = __builtin_amdgcn_mfma_f32_16x16x32_bf16(                \
            afr[mi][0], bfr[ni][0], acc[mi][ni], 0, 0, 0);                    \
        acc[mi][ni] = __builtin_amdgcn_mfma_f32_16x16x32_bf16(                \
            afr[mi][1], bfr[ni][1], acc[mi][ni], 0, 0, 0); }                  \
    __builtin_amdgcn_s_setprio(0);                                            \
    _Pragma("unroll") for (int mi = 0; mi < 4; mi++) {                        \
      afr[mi][0] = *(const short8*)(baA + offA0 + 8192 + mi * 2048);          \
      afr[mi][1] = *(const short8*)(baA + offA1 + 8192 + mi * 2048); }        \
    asm volatile("s_waitcnt lgkmcnt(0)" ::: "memory");                        \
    __builtin_amdgcn_sched_barrier(0);                                        \
    __builtin_amdgcn_s_barrier();                                             \
    __builtin_amdgcn_sched_barrier(0);                                        \
    if (DOSTAGE) { STAGE((t) + 2, (buf)); }                                   \
    __builtin_amdgcn_sched_barrier(0);                                        \
    __builtin_amdgcn_s_setprio(1);                                            \
    _Pragma("unroll") for (int mi = 0; mi < 4; mi++)                          \
      _Pragma("unroll") for (int ni = 0; ni < 4; ni++) {                      \
        acc[mi + 4][ni] = __builtin_amdgcn_mfma_f32_16x16x32_bf16(            \
            afr[mi][0], bfr[ni][0], acc[mi + 4][ni], 0, 0, 0);                \
        acc[mi + 4][ni] = __builtin_amdgcn_mfma_f32_16x16x32_bf16(            \
            afr[mi][1], bfr[ni][1], acc[mi + 4][ni], 0, 0, 0); }              \
    __builtin_amdgcn_s_setprio(0);                                            \
  } while (0)

#pragma unroll 2
  for (int t = 0; t < 6; ++t) KITER(t, (t & 1), 8, 1);
  KITER(6, 0, 8, 0);
  KITER(7, 1, 0, 0);
#undef KITER
#undef STAGE

  // epilogue: C frag row = (lane>>4)*4 + j, col = lane&15
#pragma unroll
  for (int mi = 0; mi < 8; mi++) {
    size_t row = rowBase + wm * 128 + mi * 16 + ((lane >> 4) << 2);
#pragma unroll
    for (int ni = 0; ni < 4; ni++) {
      int col = colBase + wn * 64 + ni * 16 + (lane & 15);
#pragma unroll
      for (int j = 0; j < 4; j++)
        out[(row + j) * VOCAB_ + col] = acc[mi][ni][j];
    }
  }
}

extern "C" void kernel_launch(void* const* d_in, const int* in_sizes, int n_in,
                              void* d_out, int out_size, void* d_ws, size_t ws_size,
                              hipStream_t stream) {
  const float* enc = (const float*)d_in[0];
  const float* dec = (const float*)d_in[1];
  const float* W1  = (const float*)d_in[2];
  const float* b1  = (const float*)d_in[3];
  const float* W2  = (const float*)d_in[4];
  const float* b2  = (const float*)d_in[5];
  float* out = (float*)d_out;

  char* ws = (char*)d_ws;
  float* encP  = (float*)ws;                                   // 1024*512*4 = 2 MiB
  float* decPb = (float*)(ws + (2u << 20));                    // 256*512*4 = 512 KiB
  __hip_bfloat16* W2T = (__hip_bfloat16*)(ws + (2u << 20) + (512u << 10));          // 2 MiB
  __hip_bfloat16* H   = (__hip_bfloat16*)(ws + (2u << 20) + (512u << 10) + (2u << 20)); // 64 MiB

  static int smem_set = 0;
  if (!smem_set) {
    (void)hipFuncSetAttribute((const void*)joint_gemm,
                              hipFuncAttributeMaxDynamicSharedMemorySize, 131072);
    smem_set = 1;
  }

  proj_kernel<<<dim3(4, 80), 256, 0, stream>>>(enc, dec, W1, b1, encP, decPb);
  w2t_kernel<<<dim3(64, 16), 256, 0, stream>>>(W2, W2T);
  hidden_kernel<<<16384, 256, 0, stream>>>(encP, decPb, H);
  joint_gemm<<<dim3(2048), 512, 131072, stream>>>(H, W2T, b2, out);
}

// Round 3
// 724.690 us; speedup vs baseline: 1.0831x; 1.0211x over previous
//
#include <hip/hip_runtime.h>
#include <hip/hip_bf16.h>

#define B_  4
#define T_  256
#define U_  64
#define D_  512
#define INNER_ 512
#define VOCAB_ 2048

// ---------------- types ----------------
typedef __attribute__((ext_vector_type(8))) short short8;   // 8 bf16 (4 VGPRs)
typedef __attribute__((ext_vector_type(4))) float f32x4;

// ---------------- pass 1: projections (fp32) ----------------
__global__ __launch_bounds__(256) void proj_kernel(
    const float* __restrict__ enc, const float* __restrict__ dec,
    const float* __restrict__ W1, const float* __restrict__ b1,
    float* __restrict__ encP, float* __restrict__ decPb) {
  int ct = blockIdx.x;   // 0..3 col tiles of 128
  int rt = blockIdx.y;   // 0..79 row tiles of 16 (64 enc + 16 dec)
  const float* src; float* dst; int kOff; int addB1; int rowBase;
  if (rt < 64) { src = enc; dst = encP; kOff = 0; addB1 = 0; rowBase = rt * 16; }
  else { src = dec; dst = decPb; kOff = D_; addB1 = 1; rowBase = (rt - 64) * 16; }

  __shared__ float As[16][D_];  // 32 KiB
  int tid = threadIdx.x;
  const float4* s4 = (const float4*)(src + (size_t)rowBase * D_);
  float4* a4 = (float4*)(&As[0][0]);
#pragma unroll
  for (int i = 0; i < 8; i++) a4[tid + 256 * i] = s4[tid + 256 * i];
  __syncthreads();

  int colQ = (tid & 31) * 4;        // 4 consecutive cols within 128-tile
  int col = ct * 128 + colQ;
  int r0 = (tid >> 5) * 2;          // 2 rows
  float a00=0,a01=0,a02=0,a03=0, a10=0,a11=0,a12=0,a13=0;
  const float* Wp = W1 + (size_t)kOff * INNER_ + col;
#pragma unroll 4
  for (int k = 0; k < D_; k++) {
    float4 w = *(const float4*)(Wp + (size_t)k * INNER_);
    float e0 = As[r0][k], e1 = As[r0 + 1][k];
    a00 += e0 * w.x; a01 += e0 * w.y; a02 += e0 * w.z; a03 += e0 * w.w;
    a10 += e1 * w.x; a11 += e1 * w.y; a12 += e1 * w.z; a13 += e1 * w.w;
  }
  float4 bb = {0,0,0,0};
  if (addB1) bb = *(const float4*)(b1 + col);
  float4 o0 = {a00 + bb.x, a01 + bb.y, a02 + bb.z, a03 + bb.w};
  float4 o1 = {a10 + bb.x, a11 + bb.y, a12 + bb.z, a13 + bb.w};
  *(float4*)(dst + (size_t)(rowBase + r0) * INNER_ + col) = o0;
  *(float4*)(dst + (size_t)(rowBase + r0 + 1) * INNER_ + col) = o1;
}

// ---------------- pass 1b: W2 (512x2048 f32) -> W2T (2048x512 bf16) ----------------
__global__ __launch_bounds__(256) void w2t_kernel(
    const float* __restrict__ W2, __hip_bfloat16* __restrict__ W2T) {
  __shared__ float tile[32][33];
  int vBase = blockIdx.x * 32;  // 64
  int kBase = blockIdx.y * 32;  // 16
  int tx = threadIdx.x & 31, ty = threadIdx.x >> 5;  // 32 x 8
#pragma unroll
  for (int i = 0; i < 32; i += 8)
    tile[ty + i][tx] = W2[(size_t)(kBase + ty + i) * VOCAB_ + vBase + tx];
  __syncthreads();
#pragma unroll
  for (int i = 0; i < 32; i += 8)
    W2T[(size_t)(vBase + ty + i) * INNER_ + kBase + tx] = __float2bfloat16(tile[tx][ty + i]);
}

// ---------------- pass 2: hidden H[r][k] = tanh(encP[bt][k] + decPb[b*64+u][k]) ----------------
__global__ __launch_bounds__(256) void hidden_kernel(
    const float* __restrict__ encP, const float* __restrict__ decPb,
    __hip_bfloat16* __restrict__ H) {
  int gid = blockIdx.x * 256 + threadIdx.x;  // 4,194,304 total
  int k0 = (gid & 63) * 8;
  int r = gid >> 6;            // row in [0, 65536)
  int u = r & 63;
  int bt = r >> 6;             // b*T + t
  int b = bt >> 8;             // T = 256
  const float4* e = (const float4*)(encP + (size_t)bt * 512 + k0);
  const float4* dv = (const float4*)(decPb + (size_t)(b * 64 + u) * 512 + k0);
  float4 e0 = e[0], e1 = e[1];
  float4 d0 = dv[0], d1 = dv[1];
  union { __hip_bfloat16 h[8]; uint4 v; } p;
  p.h[0] = __float2bfloat16(tanhf(e0.x + d0.x));
  p.h[1] = __float2bfloat16(tanhf(e0.y + d0.y));
  p.h[2] = __float2bfloat16(tanhf(e0.z + d0.z));
  p.h[3] = __float2bfloat16(tanhf(e0.w + d0.w));
  p.h[4] = __float2bfloat16(tanhf(e1.x + d1.x));
  p.h[5] = __float2bfloat16(tanhf(e1.y + d1.y));
  p.h[6] = __float2bfloat16(tanhf(e1.z + d1.z));
  p.h[7] = __float2bfloat16(tanhf(e1.w + d1.w));
  *(uint4*)((__hip_bfloat16*)H + (size_t)r * 512 + k0) = p.v;
}

// ---------------- pass 3: main GEMM: out = H(65536x512) * W2T^T + b2 ----------------
// 256x256 tile, 8 waves (2x4), BK=64, double-buffered LDS (128 KiB),
// counted vmcnt (T4), XOR-swizzled LDS via pre-swizzled global source (T2),
// setprio around MFMA clusters (T5), bijective XCD swizzle (T1).
// NEW this round: LDS-repack epilogue -> 1 KiB contiguous dwordx4 stores.
__device__ inline void gload_lds16(const void* g, void* l) {
  __builtin_amdgcn_global_load_lds(
      (const __attribute__((address_space(1))) unsigned int*)g,
      (__attribute__((address_space(3))) unsigned int*)l, 16, 0, 0);
}

__global__ __launch_bounds__(512, 2) void joint_gemm(
    const __hip_bfloat16* __restrict__ H, const __hip_bfloat16* __restrict__ W2T,
    const float* __restrict__ b2, float* __restrict__ out) {
  extern __shared__ char smem[];  // 128 KiB: A[2][256][64] bf16, B[2][256][64] bf16
  int tid = threadIdx.x;
  int lane = tid & 63, wave = tid >> 6;     // 8 waves
  int wm = wave >> 2, wn = wave & 3;        // 2 x 4 wave grid; per-wave 128x64 output

  // T1: XCD-aware bijective swizzle, nwg = 2048 (divisible by 8)
  int bid = blockIdx.x;
  int wg = (bid & 7) * 256 + (bid >> 3);
  int rt = wg >> 3;          // 0..255 (M tiles)
  int ct = wg & 7;           // 0..7   (N tiles)
  size_t rowBase = (size_t)rt * 256;
  int colBase = ct * 256;

  // ---- staging setup (per-thread) ----
  // Thread stages rows j*64 + (tid>>3), swizzled k-slot (tid&7)^(row&7).
  // LDS dest stays linear (global_load_lds requirement); source is pre-swizzled.
  int srow = tid >> 3;                          // 0..63
  int kswz = ((tid & 7) ^ (srow & 7)) * 8;      // bf16 element offset within 64-wide k
  const __hip_bfloat16* pA = H   + (rowBase + srow) * 512 + kswz;
  const __hip_bfloat16* pB = W2T + (size_t)(colBase + srow) * 512 + kswz;
  __hip_bfloat16* ldsA = (__hip_bfloat16*)smem;
  __hip_bfloat16* ldsB = (__hip_bfloat16*)(smem + 65536);
  int stageRow = wave * 8;  // wave-uniform LDS base row within each 64-row unit

#define STAGE(t, buf) do {                                                    \
    const __hip_bfloat16* ga = pA + (size_t)(t) * 64;                         \
    const __hip_bfloat16* gb = pB + (size_t)(t) * 64;                         \
    __hip_bfloat16* la = ldsA + (buf) * 16384 + stageRow * 64;                \
    __hip_bfloat16* lb = ldsB + (buf) * 16384 + stageRow * 64;                \
    _Pragma("unroll")                                                         \
    for (int j = 0; j < 4; j++) {                                             \
      gload_lds16(ga + (size_t)j * 64 * 512, la + j * 64 * 64);               \
      gload_lds16(gb + (size_t)j * 64 * 512, lb + j * 64 * 64);               \
    } } while (0)

  // ---- fragment ds_read byte offsets (swizzle-matched) ----
  // frag row r, k-slot gs = ks*4 + (lane>>4): byte = r*128 + ((gs*16) ^ ((r&7)*16))
  int lrA = wm * 128 + (lane & 15);
  int lrB = wn * 64 + (lane & 15);
  int sx = (lane & 7) * 16;                 // (r&7)*16 — same for all mi/ni (steps of 16 rows)
  int q16 = (lane >> 4) * 16;
  int offA0 = lrA * 128 + (q16 ^ sx);
  int offA1 = lrA * 128 + ((64 + q16) ^ sx);
  int offB0 = lrB * 128 + (q16 ^ sx);
  int offB1 = lrB * 128 + ((64 + q16) ^ sx);

  // ---- acc init with bias ----
  float bv[4];
#pragma unroll
  for (int ni = 0; ni < 4; ni++) bv[ni] = b2[colBase + wn * 64 + ni * 16 + (lane & 15)];
  f32x4 acc[8][4];
#pragma unroll
  for (int mi = 0; mi < 8; mi++)
#pragma unroll
    for (int ni = 0; ni < 4; ni++)
      acc[mi][ni] = (f32x4){bv[ni], bv[ni], bv[ni], bv[ni]};

  // drain bias loads so the vmcnt bookkeeping below is exact
  asm volatile("s_waitcnt vmcnt(0)" ::: "memory");
  __builtin_amdgcn_sched_barrier(0);

  // prologue: tiles 0 and 1 in flight (8 loads/wave each)
  STAGE(0, 0);
  STAGE(1, 1);

  // Per K-tile: vmcnt(8)+barrier (tile landed) -> ds_read frags -> MFMA lo ->
  // ds_read hi -> lgkmcnt(0)+barrier (all reads done) -> restage t+2 into this
  // buffer -> MFMA hi. Loads for t+1 stay in flight across everything (T4).
#define KITER(t, buf, VMC, DOSTAGE) do {                                      \
    asm volatile("s_waitcnt vmcnt(" #VMC ")" ::: "memory");                   \
    __builtin_amdgcn_sched_barrier(0);                                        \
    __builtin_amdgcn_s_barrier();                                             \
    __builtin_amdgcn_sched_barrier(0);                                        \
    const char* baA = (const char*)ldsA + (buf) * 32768;                      \
    const char* baB = (const char*)ldsB + (buf) * 32768;                      \
    short8 bfr[4][2], afr[4][2];                                              \
    _Pragma("unroll") for (int ni = 0; ni < 4; ni++) {                        \
      bfr[ni][0] = *(const short8*)(baB + offB0 + ni * 2048);                 \
      bfr[ni][1] = *(const short8*)(baB + offB1 + ni * 2048); }               \
    _Pragma("unroll") for (int mi = 0; mi < 4; mi++) {                        \
      afr[mi][0] = *(const short8*)(baA + offA0 + mi * 2048);                 \
      afr[mi][1] = *(const short8*)(baA + offA1 + mi * 2048); }               \
    __builtin_amdgcn_s_setprio(1);                                            \
    _Pragma("unroll") for (int mi = 0; mi < 4; mi++)                          \
      _Pragma("unroll") for (int ni = 0; ni < 4; ni++) {                      \
        acc[mi][ni] = __builtin_amdgcn_mfma_f32_16x16x32_bf16(                \
            afr[mi][0], bfr[ni][0], acc[mi][ni], 0, 0, 0);                    \
        acc[mi][ni] = __builtin_amdgcn_mfma_f32_16x16x32_bf16(                \
            afr[mi][1], bfr[ni][1], acc[mi][ni], 0, 0, 0); }                  \
    __builtin_amdgcn_s_setprio(0);                                            \
    _Pragma("unroll") for (int mi = 0; mi < 4; mi++) {                        \
      afr[mi][0] = *(const short8*)(baA + offA0 + 8192 + mi * 2048);          \
      afr[mi][1] = *(const short8*)(baA + offA1 + 8192 + mi * 2048); }        \
    asm volatile("s_waitcnt lgkmcnt(0)" ::: "memory");                        \
    __builtin_amdgcn_sched_barrier(0);                                        \
    __builtin_amdgcn_s_barrier();                                             \
    __builtin_amdgcn_sched_barrier(0);                                        \
    if (DOSTAGE) { STAGE((t) + 2, (buf)); }                                   \
    __builtin_amdgcn_sched_barrier(0);                                        \
    __builtin_amdgcn_s_setprio(1);                                            \
    _Pragma("unroll") for (int mi = 0; mi < 4; mi++)                          \
      _Pragma("unroll") for (int ni = 0; ni < 4; ni++) {                      \
        acc[mi + 4][ni] = __builtin_amdgcn_mfma_f32_16x16x32_bf16(            \
            afr[mi][0], bfr[ni][0], acc[mi + 4][ni], 0, 0, 0);                \
        acc[mi + 4][ni] = __builtin_amdgcn_mfma_f32_16x16x32_bf16(            \
            afr[mi][1], bfr[ni][1], acc[mi + 4][ni], 0, 0, 0); }              \
    __builtin_amdgcn_s_setprio(0);                                            \
  } while (0)

#pragma unroll 2
  for (int t = 0; t < 6; ++t) KITER(t, (t & 1), 8, 1);
  KITER(6, 0, 8, 0);
  KITER(7, 1, 0, 0);
#undef KITER
#undef STAGE

  // ---- epilogue: LDS repack -> fully coalesced 1 KiB/wave dwordx4 stores ----
  // 4 rounds of a 64x256 f32 panel (stride 260 dwords: 16B-aligned rows,
  // 2-way-free banks on fragment writes, conflict-free b128 reads).
  // Round r covers tile rows [r*64, r*64+64): waves with wm==r>>1 write
  // their acc[mih..mih+3][*] (mih = (r&1)*4), then all 512 threads stream
  // the panel out as contiguous rows (64 lanes x 16 B = one 1 KiB row).
  {
    float* lp = (float*)smem;
    float* outBase = out + rowBase * VOCAB_ + colBase;
#pragma unroll
    for (int r = 0; r < 4; r++) {
      __syncthreads();                       // prev round's reads complete
      if (wm == (r >> 1)) {
        int mih = (r & 1) * 4;
#pragma unroll
        for (int q = 0; q < 4; q++) {
          int lrow0 = q * 16 + ((lane >> 4) << 2);
#pragma unroll
          for (int ni = 0; ni < 4; ni++) {
            int col = wn * 64 + ni * 16 + (lane & 15);
            f32x4 v = acc[mih + q][ni];
#pragma unroll
            for (int j = 0; j < 4; j++)
              lp[(lrow0 + j) * 260 + col] = v[j];
          }
        }
      }
      __syncthreads();                       // panel ready
#pragma unroll
      for (int i = 0; i < 8; i++) {
        int c = tid + 512 * i;               // [0,4096): row = c>>6, chunk = c&63
        int row = c >> 6, cc = c & 63;
        f32x4 v = *(const f32x4*)(lp + row * 260 + cc * 4);
        *(float4*)(outBase + (size_t)(r * 64 + row) * VOCAB_ + cc * 4) =
            (float4){v[0], v[1], v[2], v[3]};
      }
    }
  }
}

extern "C" void kernel_launch(void* const* d_in, const int* in_sizes, int n_in,
                              void* d_out, int out_size, void* d_ws, size_t ws_size,
                              hipStream_t stream) {
  const float* enc = (const float*)d_in[0];
  const float* dec = (const float*)d_in[1];
  const float* W1  = (const float*)d_in[2];
  const float* b1  = (const float*)d_in[3];
  const float* W2  = (const float*)d_in[4];
  const float* b2  = (const float*)d_in[5];
  float* out = (float*)d_out;

  char* ws = (char*)d_ws;
  float* encP  = (float*)ws;                                   // 1024*512*4 = 2 MiB
  float* decPb = (float*)(ws + (2u << 20));                    // 256*512*4 = 512 KiB
  __hip_bfloat16* W2T = (__hip_bfloat16*)(ws + (2u << 20) + (512u << 10));          // 2 MiB
  __hip_bfloat16* H   = (__hip_bfloat16*)(ws + (2u << 20) + (512u << 10) + (2u << 20)); // 64 MiB

  static int smem_set = 0;
  if (!smem_set) {
    (void)hipFuncSetAttribute((const void*)joint_gemm,
                              hipFuncAttributeMaxDynamicSharedMemorySize, 131072);
    smem_set = 1;
  }

  proj_kernel<<<dim3(4, 80), 256, 0, stream>>>(enc, dec, W1, b1, encP, decPb);
  w2t_kernel<<<dim3(64, 16), 256, 0, stream>>>(W2, W2T);
  hidden_kernel<<<16384, 256, 0, stream>>>(encP, decPb, H);
  joint_gemm<<<dim3(2048), 512, 131072, stream>>>(H, W2T, b2, out);
}